// Round 3
// baseline (1137.439 us; speedup 1.0000x reference)
//
#include <hip/hip_runtime.h>

// ---------- types ----------
typedef __bf16 bf16x8 __attribute__((ext_vector_type(8)));
typedef float f32x4 __attribute__((ext_vector_type(4)));
typedef unsigned short ushort8 __attribute__((ext_vector_type(8)));

__device__ __forceinline__ unsigned short f32_to_bf16u(float f) {
  unsigned int u = __float_as_uint(f);
  u += 0x7fffu + ((u >> 16) & 1u);   // RNE; no NaN inputs here
  return (unsigned short)(u >> 16);
}

// async global->LDS, 16B per lane. LDS dest is wave-uniform base + lane*16.
__device__ __forceinline__ void async_copy16(const void* gptr, void* lptr) {
  __builtin_amdgcn_global_load_lds(
      (__attribute__((address_space(1))) void*)(unsigned long long)gptr,
      (__attribute__((address_space(3))) void*)(unsigned long long)lptr,
      16, 0, 0);
}

// ---------- LoRA B@A precompute: Wba[li][o][c] = sum_r B[o][r]*A[r][c] ----------
__global__ __launch_bounds__(256) void lora_ba_kernel(
    const float* __restrict__ lora_a, const float* __restrict__ lora_b,
    float* __restrict__ Wba)
{
  const int bid = blockIdx.x;          // 3*1024
  const int li = bid >> 10;
  const int o = bid & 1023;
  const float* B = lora_b + li * 32768 + o * 32;
  const float* A = lora_a + li * 32768;
  const int c = threadIdx.x * 4;
  float4 acc = {0.f, 0.f, 0.f, 0.f};
#pragma unroll
  for (int r = 0; r < 32; r++) {
    const float br = B[r];
    const float4 a = *(const float4*)&A[r * 1024 + c];
    acc.x += br * a.x; acc.y += br * a.y; acc.z += br * a.z; acc.w += br * a.w;
  }
  *(float4*)&Wba[((size_t)li << 20) + o * 1024 + c] = acc;
}

// ---------- dequant all 18 weights (int4 -> bf16 [out,in]), LoRA pre-merged ----------
__global__ __launch_bounds__(256) void dequant_kernel(
    const int* __restrict__ wq4, const float* __restrict__ wnorm,
    const float* __restrict__ Wba, unsigned short* __restrict__ Wd)
{
  const int gi = blockIdx.x * 256 + threadIdx.x;   // < 18*524288
  const int w = gi >> 19;
  const int rem = gi & 524287;
  const int q = wq4[gi];
  const float norm = wnorm[(w << 8) + (rem >> 11)];
  float w0 = ((float)(q & 15) * (2.0f / 15.0f) - 1.0f) * norm;
  float w1 = ((float)(q >> 4) * (2.0f / 15.0f) - 1.0f) * norm;
  const int p = rem << 1;
  const int li = (w == 0) ? 0 : (w == 6) ? 1 : (w == 12) ? 2 : -1;
  if (li >= 0) {
    const float2 ba = *(const float2*)&Wba[((size_t)li << 20) + p];
    w0 += ba.x;
    w1 += ba.y;
  }
  const unsigned int packed =
      ((unsigned int)f32_to_bf16u(w1) << 16) | (unsigned int)f32_to_bf16u(w0);
  *(unsigned int*)&Wd[((size_t)w << 20) + p] = packed;
}

// ---------- fp32 -> bf16 cast ----------
__global__ __launch_bounds__(256) void cast_bf16_kernel(
    const float* __restrict__ x, unsigned short* __restrict__ o)
{
  const int i = blockIdx.x * 256 + threadIdx.x;
  const float4 v = ((const float4*)x)[i];
  ushort4 b;
  b.x = f32_to_bf16u(v.x);
  b.y = f32_to_bf16u(v.y);
  b.z = f32_to_bf16u(v.z);
  b.w = f32_to_bf16u(v.w);
  ((ushort4*)o)[i] = b;
}

// ---------- bf16 MFMA GEMM: C[m,n] = sum_k A[m,k]*W[n,k] ----------
// 128x128 tile, BK=64, 4 waves (2x2), wave = 4x4 of 16x16x32 MFMA.
// XCD slab swizzle (bid&7) for L2 reuse; XOR-of-row bank swizzle applied on the
// GLOBAL source column so global_load_lds's identity lane mapping yields
// conflict-free ds_read_b128. Epilogue goes through LDS for coalesced stores.
// EPIL 0: relu -> bf16. EPIL 1: +Res(fp32) -> fp32 (no relu).
template <int EPIL>
__global__ __launch_bounds__(256, 4) void gemm_bt(
    const unsigned short* __restrict__ A, const unsigned short* __restrict__ W,
    void* __restrict__ Out, const float* __restrict__ Res)
{
  constexpr int K = 1024;
  constexpr int N = 1024;
  __shared__ __align__(16) char smem[32768];
  unsigned short* As = (unsigned short*)smem;            // 128x64 bf16, 16 KB
  unsigned short* Ws = (unsigned short*)(smem + 16384);  // 128x64 bf16, 16 KB

  const int tid = threadIdx.x;
  const int lane = tid & 63;
  const int wave = tid >> 6;

  const int bid = blockIdx.x;           // 0..1023
  const int xcd = bid & 7;
  const int j = bid >> 3;               // 0..127 per-XCD sequence
  const int m0 = (xcd * 16 + (j >> 3)) * 128;
  const int n0 = (j & 7) * 128;

  const int wm = (wave >> 1) * 64;
  const int wn = (wave & 1) * 64;

  f32x4 acc[4][4];
#pragma unroll
  for (int i = 0; i < 4; i++)
#pragma unroll
    for (int jj = 0; jj < 4; jj++) acc[i][jj] = (f32x4){0.f, 0.f, 0.f, 0.f};

  const int arow = tid >> 3;
  const int acol8 = (tid & 7) ^ (arow & 7);
  const unsigned short* Ag = A + (size_t)(m0 + arow) * K + acol8 * 8;
  const unsigned short* Wg = W + (size_t)(n0 + arow) * K + acol8 * 8;
  unsigned short* Asd = &As[tid * 8];
  unsigned short* Wsd = &Ws[tid * 8];

  const int fr = lane & 15;    // m (or n) within a 16-tile
  const int q = lane >> 4;     // quad index

  for (int k0 = 0; k0 < K; k0 += 64) {
#pragma unroll
    for (int i = 0; i < 4; i++)
      async_copy16(Ag + (size_t)i * 32 * K + k0, Asd + i * 2048);
#pragma unroll
    for (int i = 0; i < 4; i++)
      async_copy16(Wg + (size_t)i * 32 * K + k0, Wsd + i * 2048);
    __syncthreads();
#pragma unroll
    for (int h = 0; h < 2; h++) {
      const int kk8 = q + h * 4;
      bf16x8 a[4], b[4];
#pragma unroll
      for (int i = 0; i < 4; i++) {
        const int row = wm + i * 16 + fr;
        a[i] = *(const bf16x8*)&As[row * 64 + ((kk8 ^ (fr & 7)) << 3)];
      }
#pragma unroll
      for (int jj = 0; jj < 4; jj++) {
        const int row = wn + jj * 16 + fr;
        b[jj] = *(const bf16x8*)&Ws[row * 64 + ((kk8 ^ (fr & 7)) << 3)];
      }
#pragma unroll
      for (int i = 0; i < 4; i++)
#pragma unroll
        for (int jj = 0; jj < 4; jj++)
          acc[i][jj] = __builtin_amdgcn_mfma_f32_16x16x32_bf16(a[i], b[jj], acc[i][jj], 0, 0, 0);
    }
    __syncthreads();  // also frees smem for epilogue reuse
  }

  // C/D layout: n = lane&15, m = (lane>>4)*4 + reg  (verified m89/m91)
  const int rq = q * 4;

  if (EPIL == 0) {
    // relu -> bf16 tile in LDS, then coalesced 16B-row stores
    unsigned short* cs = (unsigned short*)smem;  // 128x128 bf16 = 32 KB
#pragma unroll
    for (int i = 0; i < 4; i++)
#pragma unroll
      for (int r = 0; r < 4; r++) {
        const int m = wm + i * 16 + rq + r;
#pragma unroll
        for (int jj = 0; jj < 4; jj++) {
          const int n = wn + jj * 16 + fr;
          float v = acc[i][jj][r];
          v = v > 0.f ? v : 0.f;
          cs[m * 128 + n] = f32_to_bf16u(v);
        }
      }
    __syncthreads();
#pragma unroll
    for (int it = 0; it < 8; it++) {
      const int flat16 = it * 256 + tid;     // 16B units, 2048 total
      const int row = flat16 >> 4;           // 16 units per 256B row
      const int unit = flat16 & 15;
      const ushort8 v = *(const ushort8*)&cs[flat16 * 8];
      *(ushort8*)&((unsigned short*)Out)[(size_t)(m0 + row) * N + n0 + unit * 8] = v;
    }
  } else {
    // fp32 + residual, two 64-row halves through 32 KB LDS
    float* cf = (float*)smem;  // 64x128 fp32 = 32 KB
#pragma unroll
    for (int half = 0; half < 2; half++) {
      if ((wave >> 1) == half) {
#pragma unroll
        for (int i = 0; i < 4; i++)
#pragma unroll
          for (int r = 0; r < 4; r++) {
            const int mrel = i * 16 + rq + r;
#pragma unroll
            for (int jj = 0; jj < 4; jj++)
              cf[mrel * 128 + wn + jj * 16 + fr] = acc[i][jj][r];
          }
      }
      __syncthreads();
#pragma unroll
      for (int it = 0; it < 8; it++) {
        const int flat4 = it * 256 + tid;    // float4 units, 2048 total
        const int row = flat4 >> 5;          // 32 units per 128-float row
        const int unit = flat4 & 31;
        const size_t g = (size_t)(m0 + half * 64 + row) * N + n0 + unit * 4;
        float4 v = *(const float4*)&cf[flat4 * 4];
        const float4 rr = *(const float4*)&Res[g];
        v.x += rr.x; v.y += rr.y; v.z += rr.z; v.w += rr.w;
        *(float4*)&((float*)Out)[g] = v;
      }
      __syncthreads();
    }
  }
}

// ---------- LayerNorm (fp32 in, writes bf16 + fp32) ----------
__global__ __launch_bounds__(256) void ln_kernel(
    const float* __restrict__ y, const float* __restrict__ gamma,
    const float* __restrict__ beta, unsigned short* __restrict__ h_bf,
    float* __restrict__ h_f32)
{
  const int row = blockIdx.x;
  const int tid = threadIdx.x;
  const size_t base = (size_t)row * 1024;
  const float4 v = ((const float4*)(y + base))[tid];
  float s = v.x + v.y + v.z + v.w;
  float s2 = v.x * v.x + v.y * v.y + v.z * v.z + v.w * v.w;
#pragma unroll
  for (int off = 32; off > 0; off >>= 1) {
    s += __shfl_down(s, off, 64);
    s2 += __shfl_down(s2, off, 64);
  }
  __shared__ float red[8];
  if ((tid & 63) == 0) {
    red[tid >> 6] = s;
    red[4 + (tid >> 6)] = s2;
  }
  __syncthreads();
  s = red[0] + red[1] + red[2] + red[3];
  s2 = red[4] + red[5] + red[6] + red[7];
  const float mu = s * (1.0f / 1024.0f);
  const float var = s2 * (1.0f / 1024.0f) - mu * mu;
  const float rs = rsqrtf(var + 1e-5f);
  const float4 g = ((const float4*)gamma)[tid];
  const float4 bb = ((const float4*)beta)[tid];
  float4 o;
  o.x = (v.x - mu) * rs * g.x + bb.x;
  o.y = (v.y - mu) * rs * g.y + bb.y;
  o.z = (v.z - mu) * rs * g.z + bb.z;
  o.w = (v.w - mu) * rs * g.w + bb.w;
  ((float4*)(h_f32 + base))[tid] = o;
  ushort4 ob;
  ob.x = f32_to_bf16u(o.x);
  ob.y = f32_to_bf16u(o.y);
  ob.z = f32_to_bf16u(o.z);
  ob.w = f32_to_bf16u(o.w);
  ((ushort4*)(h_bf + base))[tid] = ob;
}

// ---------- launch ----------
extern "C" void kernel_launch(void* const* d_in, const int* in_sizes, int n_in,
                              void* d_out, int out_size, void* d_ws, size_t ws_size,
                              hipStream_t stream)
{
  const float* x = (const float*)d_in[0];
  const int* wq4 = (const int*)d_in[1];
  const float* wnorm = (const float*)d_in[2];
  const float* lora_a = (const float*)d_in[3];
  const float* lora_b = (const float*)d_in[4];
  const float* ln_g = (const float*)d_in[5];
  const float* ln_b = (const float*)d_in[6];
  float* out = (float*)d_out;

  char* ws = (char*)d_ws;
  unsigned short* Wd   = (unsigned short*)(ws);              // 36 MiB
  unsigned short* h_bf = (unsigned short*)(ws + 37748736);   // 32 MiB
  unsigned short* t1   = (unsigned short*)(ws + 71303168);   // 32 MiB
  unsigned short* t2   = (unsigned short*)(ws + 104857600);  // 32 MiB
  float* h_f32         = (float*)(ws + 138412032);           // 64 MiB
  // Wba aliases h_f32's space: only live during dequant phase, before first LN.
  float* Wba           = (float*)(ws + 138412032);           // 12 MiB used

  lora_ba_kernel<<<3072, 256, 0, stream>>>(lora_a, lora_b, Wba);
  dequant_kernel<<<36864, 256, 0, stream>>>(wq4, wnorm, Wba, Wd);
  cast_bf16_kernel<<<16384, 256, 0, stream>>>(x, h_bf);

  const unsigned short* hb = h_bf;
  const float* hres = x;
  for (int b = 0; b < 6; b++) {
    const unsigned short* W0 = Wd + (size_t)(3 * b + 0) * 1048576;
    const unsigned short* W1 = Wd + (size_t)(3 * b + 1) * 1048576;
    const unsigned short* W2 = Wd + (size_t)(3 * b + 2) * 1048576;
    gemm_bt<0><<<1024, 256, 0, stream>>>(hb, W0, t1, nullptr);
    gemm_bt<0><<<1024, 256, 0, stream>>>(t1, W1, t2, nullptr);
    gemm_bt<1><<<1024, 256, 0, stream>>>(t2, W2, out, hres);
    if (b < 5) {
      ln_kernel<<<16384, 256, 0, stream>>>(out, ln_g + b * 1024, ln_b + b * 1024,
                                           h_bf, h_f32);
      hb = h_bf;
      hres = h_f32;
    }
  }
  (void)in_sizes; (void)n_in; (void)out_size; (void)ws_size;
}

// Round 4
// 931.636 us; speedup vs baseline: 1.2209x; 1.2209x over previous
//
#include <hip/hip_runtime.h>

// ---------- types ----------
typedef __bf16 bf16x8 __attribute__((ext_vector_type(8)));
typedef float f32x4 __attribute__((ext_vector_type(4)));

__device__ __forceinline__ unsigned short f32_to_bf16u(float f) {
  unsigned int u = __float_as_uint(f);
  u += 0x7fffu + ((u >> 16) & 1u);   // RNE; no NaN inputs here
  return (unsigned short)(u >> 16);
}
__device__ __forceinline__ float bf16u_to_f32(unsigned short s) {
  return __uint_as_float((unsigned int)s << 16);
}

// async global->LDS, 16B per lane. LDS dest is wave-uniform base + lane*16.
__device__ __forceinline__ void async_copy16(const void* gptr, void* lptr) {
  __builtin_amdgcn_global_load_lds(
      (__attribute__((address_space(1))) void*)(unsigned long long)gptr,
      (__attribute__((address_space(3))) void*)(unsigned long long)lptr,
      16, 0, 0);
}

// ---------- LoRA B@A precompute: Wba[li][o][c] = sum_r B[o][r]*A[r][c] ----------
__global__ __launch_bounds__(256) void lora_ba_kernel(
    const float* __restrict__ lora_a, const float* __restrict__ lora_b,
    float* __restrict__ Wba)
{
  const int bid = blockIdx.x;          // 3*1024
  const int li = bid >> 10;
  const int o = bid & 1023;
  const float* B = lora_b + li * 32768 + o * 32;
  const float* A = lora_a + li * 32768;
  const int c = threadIdx.x * 4;
  float4 acc = {0.f, 0.f, 0.f, 0.f};
#pragma unroll
  for (int r = 0; r < 32; r++) {
    const float br = B[r];
    const float4 a = *(const float4*)&A[r * 1024 + c];
    acc.x += br * a.x; acc.y += br * a.y; acc.z += br * a.z; acc.w += br * a.w;
  }
  *(float4*)&Wba[((size_t)li << 20) + o * 1024 + c] = acc;
}

// ---------- dequant all 18 weights (int4 -> bf16 [out,in]), LoRA pre-merged ----------
__global__ __launch_bounds__(256) void dequant_kernel(
    const int* __restrict__ wq4, const float* __restrict__ wnorm,
    const float* __restrict__ Wba, unsigned short* __restrict__ Wd)
{
  const int gi = blockIdx.x * 256 + threadIdx.x;   // < 18*524288
  const int w = gi >> 19;
  const int rem = gi & 524287;
  const int q = wq4[gi];
  const float norm = wnorm[(w << 8) + (rem >> 11)];
  float w0 = ((float)(q & 15) * (2.0f / 15.0f) - 1.0f) * norm;
  float w1 = ((float)(q >> 4) * (2.0f / 15.0f) - 1.0f) * norm;
  const int p = rem << 1;
  const int li = (w == 0) ? 0 : (w == 6) ? 1 : (w == 12) ? 2 : -1;
  if (li >= 0) {
    const float2 ba = *(const float2*)&Wba[((size_t)li << 20) + p];
    w0 += ba.x;
    w1 += ba.y;
  }
  const unsigned int packed =
      ((unsigned int)f32_to_bf16u(w1) << 16) | (unsigned int)f32_to_bf16u(w0);
  *(unsigned int*)&Wd[((size_t)w << 20) + p] = packed;
}

// ---------- fp32 -> bf16 cast ----------
__global__ __launch_bounds__(256) void cast_bf16_kernel(
    const float* __restrict__ x, unsigned short* __restrict__ o)
{
  const int i = blockIdx.x * 256 + threadIdx.x;
  const float4 v = ((const float4*)x)[i];
  ushort4 b;
  b.x = f32_to_bf16u(v.x);
  b.y = f32_to_bf16u(v.y);
  b.z = f32_to_bf16u(v.z);
  b.w = f32_to_bf16u(v.w);
  ((ushort4*)o)[i] = b;
}

// ---------- bf16 MFMA GEMM: C[m,n] = sum_k A[m,k]*W[n,k] ----------
// 128x128 tile, BK=64, 4 waves (2x2), wave = 4x4 of 16x16x32 MFMA.
// XCD slab swizzle (bid&7) for L2 reuse; XOR-of-row bank swizzle applied on
// the GLOBAL source column (global_load_lds lane mapping is identity) so
// ds_read_b128 is conflict-free. Direct-store epilogue (LDS epilogue measured
// slower in R3: extra barriers + 8-way ds_write conflicts).
// EPIL 0: relu -> bf16. EPIL 1: + Res(bf16) -> bf16. EPIL 2: + Res(bf16) -> fp32.
template <int EPIL>
__global__ __launch_bounds__(256, 4) void gemm_bt(
    const unsigned short* __restrict__ A, const unsigned short* __restrict__ W,
    void* __restrict__ Out, const unsigned short* __restrict__ Res)
{
  constexpr int K = 1024;
  constexpr int N = 1024;
  __shared__ unsigned short As[128 * 64];  // 16 KB
  __shared__ unsigned short Ws[128 * 64];  // 16 KB

  const int tid = threadIdx.x;
  const int lane = tid & 63;
  const int wave = tid >> 6;

  const int bid = blockIdx.x;           // 0..1023
  const int xcd = bid & 7;
  const int j = bid >> 3;               // 0..127 per-XCD sequence
  const int m0 = (xcd * 16 + (j >> 3)) * 128;
  const int n0 = (j & 7) * 128;

  const int wm = (wave >> 1) * 64;
  const int wn = (wave & 1) * 64;

  f32x4 acc[4][4];
#pragma unroll
  for (int i = 0; i < 4; i++)
#pragma unroll
    for (int jj = 0; jj < 4; jj++) acc[i][jj] = (f32x4){0.f, 0.f, 0.f, 0.f};

  const int arow = tid >> 3;
  const int acol8 = (tid & 7) ^ (arow & 7);
  const unsigned short* Ag = A + (size_t)(m0 + arow) * K + acol8 * 8;
  const unsigned short* Wg = W + (size_t)(n0 + arow) * K + acol8 * 8;
  unsigned short* Asd = &As[tid * 8];
  unsigned short* Wsd = &Ws[tid * 8];

  const int fr = lane & 15;    // m (or n) within a 16-tile
  const int q = lane >> 4;     // quad index

  for (int k0 = 0; k0 < K; k0 += 64) {
#pragma unroll
    for (int i = 0; i < 4; i++)
      async_copy16(Ag + (size_t)i * 32 * K + k0, Asd + i * 2048);
#pragma unroll
    for (int i = 0; i < 4; i++)
      async_copy16(Wg + (size_t)i * 32 * K + k0, Wsd + i * 2048);
    __syncthreads();
#pragma unroll
    for (int h = 0; h < 2; h++) {
      const int kk8 = q + h * 4;
      bf16x8 a[4], b[4];
#pragma unroll
      for (int i = 0; i < 4; i++) {
        const int row = wm + i * 16 + fr;
        a[i] = *(const bf16x8*)&As[row * 64 + ((kk8 ^ (fr & 7)) << 3)];
      }
#pragma unroll
      for (int jj = 0; jj < 4; jj++) {
        const int row = wn + jj * 16 + fr;
        b[jj] = *(const bf16x8*)&Ws[row * 64 + ((kk8 ^ (fr & 7)) << 3)];
      }
#pragma unroll
      for (int i = 0; i < 4; i++)
#pragma unroll
        for (int jj = 0; jj < 4; jj++)
          acc[i][jj] = __builtin_amdgcn_mfma_f32_16x16x32_bf16(a[i], b[jj], acc[i][jj], 0, 0, 0);
    }
    __syncthreads();
  }

  // C/D layout: n = lane&15, m = (lane>>4)*4 + reg  (verified m89/m91)
  const int rq = q * 4;
#pragma unroll
  for (int i = 0; i < 4; i++) {
#pragma unroll
    for (int r = 0; r < 4; r++) {
      const int m = m0 + wm + i * 16 + rq + r;
#pragma unroll
      for (int jj = 0; jj < 4; jj++) {
        const int n = n0 + wn + jj * 16 + fr;
        float v = acc[i][jj][r];
        if (EPIL == 0) {
          v = v > 0.f ? v : 0.f;
          ((unsigned short*)Out)[(size_t)m * N + n] = f32_to_bf16u(v);
        } else if (EPIL == 1) {
          v += bf16u_to_f32(Res[(size_t)m * N + n]);
          ((unsigned short*)Out)[(size_t)m * N + n] = f32_to_bf16u(v);
        } else {
          v += bf16u_to_f32(Res[(size_t)m * N + n]);
          ((float*)Out)[(size_t)m * N + n] = v;
        }
      }
    }
  }
}

// ---------- LayerNorm (bf16 in s, bf16 out h) ----------
__global__ __launch_bounds__(256) void ln_kernel(
    const unsigned short* __restrict__ s_bf, const float* __restrict__ gamma,
    const float* __restrict__ beta, unsigned short* __restrict__ h_bf)
{
  const int row = blockIdx.x;
  const int tid = threadIdx.x;
  const size_t base = (size_t)row * 1024;
  const ushort4 u = ((const ushort4*)(s_bf + base))[tid];
  float v0 = bf16u_to_f32(u.x), v1 = bf16u_to_f32(u.y);
  float v2 = bf16u_to_f32(u.z), v3 = bf16u_to_f32(u.w);
  float s = v0 + v1 + v2 + v3;
  float s2 = v0 * v0 + v1 * v1 + v2 * v2 + v3 * v3;
#pragma unroll
  for (int off = 32; off > 0; off >>= 1) {
    s += __shfl_down(s, off, 64);
    s2 += __shfl_down(s2, off, 64);
  }
  __shared__ float red[8];
  if ((tid & 63) == 0) {
    red[tid >> 6] = s;
    red[4 + (tid >> 6)] = s2;
  }
  __syncthreads();
  s = red[0] + red[1] + red[2] + red[3];
  s2 = red[4] + red[5] + red[6] + red[7];
  const float mu = s * (1.0f / 1024.0f);
  const float var = s2 * (1.0f / 1024.0f) - mu * mu;
  const float rs = rsqrtf(var + 1e-5f);
  const float4 g = ((const float4*)gamma)[tid];
  const float4 bb = ((const float4*)beta)[tid];
  ushort4 ob;
  ob.x = f32_to_bf16u((v0 - mu) * rs * g.x + bb.x);
  ob.y = f32_to_bf16u((v1 - mu) * rs * g.y + bb.y);
  ob.z = f32_to_bf16u((v2 - mu) * rs * g.z + bb.z);
  ob.w = f32_to_bf16u((v3 - mu) * rs * g.w + bb.w);
  ((ushort4*)(h_bf + base))[tid] = ob;
}

// ---------- launch ----------
extern "C" void kernel_launch(void* const* d_in, const int* in_sizes, int n_in,
                              void* d_out, int out_size, void* d_ws, size_t ws_size,
                              hipStream_t stream)
{
  const float* x = (const float*)d_in[0];
  const int* wq4 = (const int*)d_in[1];
  const float* wnorm = (const float*)d_in[2];
  const float* lora_a = (const float*)d_in[3];
  const float* lora_b = (const float*)d_in[4];
  const float* ln_g = (const float*)d_in[5];
  const float* ln_b = (const float*)d_in[6];
  float* out = (float*)d_out;

  char* ws = (char*)d_ws;
  unsigned short* Wd   = (unsigned short*)(ws);              // 36 MiB
  unsigned short* x_bf = (unsigned short*)(ws + 37748736);   // 32 MiB
  unsigned short* t1   = (unsigned short*)(ws + 71303168);   // 32 MiB
  unsigned short* t2   = (unsigned short*)(ws + 104857600);  // 32 MiB
  unsigned short* s_bf = (unsigned short*)(ws + 138412032);  // 32 MiB
  unsigned short* h_bf = (unsigned short*)(ws + 171966464);  // 32 MiB
  // Wba aliases s_bf: only live during dequant, before first EPIL1 write.
  float* Wba           = (float*)(ws + 138412032);           // 12 MiB used

  lora_ba_kernel<<<3072, 256, 0, stream>>>(lora_a, lora_b, Wba);
  dequant_kernel<<<36864, 256, 0, stream>>>(wq4, wnorm, Wba, Wd);
  cast_bf16_kernel<<<16384, 256, 0, stream>>>(x, x_bf);

  const unsigned short* hb = x_bf;
  const unsigned short* hres = x_bf;
  for (int b = 0; b < 6; b++) {
    const unsigned short* W0 = Wd + (size_t)(3 * b + 0) * 1048576;
    const unsigned short* W1 = Wd + (size_t)(3 * b + 1) * 1048576;
    const unsigned short* W2 = Wd + (size_t)(3 * b + 2) * 1048576;
    gemm_bt<0><<<1024, 256, 0, stream>>>(hb, W0, t1, nullptr);
    gemm_bt<0><<<1024, 256, 0, stream>>>(t1, W1, t2, nullptr);
    if (b < 5) {
      gemm_bt<1><<<1024, 256, 0, stream>>>(t2, W2, s_bf, hres);
      ln_kernel<<<16384, 256, 0, stream>>>(s_bf, ln_g + b * 1024, ln_b + b * 1024, h_bf);
      hb = h_bf;
      hres = h_bf;
    } else {
      gemm_bt<2><<<1024, 256, 0, stream>>>(t2, W2, out, hres);
    }
  }
  (void)in_sizes; (void)n_in; (void)out_size; (void)ws_size;
}